// Round 1
// baseline (2162.953 us; speedup 1.0000x reference)
//
#include <hip/hip_runtime.h>

// GraphConvBlock: 7 stacked 3x3 SAME convs over a DAG.
// Linearity trick: node with children {a,b}: conv(a,W)+conv(b,W)+2b == conv(a+b,W)+2*bias.
// Stage plan (rotating buffers, only 2 ws activations + d_out):
//   A0=OUT, A1=B0, A2=B1, A3=OUT, A4=B0, A5=B1, A6=OUT

#define TB_H 8      // output rows per block
#define TB_OC 16    // output channels per block
#define IC_CHUNK 4  // input channels staged per LDS pass

// block = 256 threads: row = tid>>5 (0..7), col pair = (tid&31)*2
template <int C_IN>
__global__ __launch_bounds__(256, 2) void conv3x3_sum_kernel(
    const float* __restrict__ in0, const float* __restrict__ in1,
    const float* __restrict__ Wt, const float* __restrict__ bias,
    const float bmult, float* __restrict__ out) {
  const int tid = threadIdx.x;
  const int row = tid >> 5;          // 0..7
  const int w0  = (tid & 31) * 2;    // 0,2,..,62
  const int h0  = blockIdx.x * TB_H;
  const int oc0 = blockIdx.y * TB_OC;
  const int n   = blockIdx.z;

  __shared__ float lds[IC_CHUNK * 10 * 66];

  float acc[TB_OC][2];
#pragma unroll
  for (int oc = 0; oc < TB_OC; ++oc) {
    acc[oc][0] = 0.f;
    acc[oc][1] = 0.f;
  }

  for (int c0 = 0; c0 < C_IN; c0 += IC_CHUNK) {
    __syncthreads();
    // ---- stage IC_CHUNK input channels (10 rows x 66 cols halo tile) ----
    for (int idx = tid; idx < IC_CHUNK * 10 * 66; idx += 256) {
      const int c  = idx % 66;
      const int t  = idx / 66;
      const int r  = t % 10;
      const int ic = t / 10;
      const int gh = h0 + r - 1;
      const int gw = c - 1;
      float v = 0.f;
      if ((unsigned)gh < 64u && (unsigned)gw < 64u) {
        const size_t off =
            ((size_t)(n * C_IN + c0 + ic) * 64 + gh) * 64 + gw;
        v = in0[off];
        if (in1) v += in1[off];  // fused child-sum
      }
      lds[idx] = v;
    }
    __syncthreads();

    // ---- compute ----
#pragma unroll
    for (int ic = 0; ic < IC_CHUNK; ++ic) {
      float xin[3][4];
#pragma unroll
      for (int dy = 0; dy < 3; ++dy)
#pragma unroll
        for (int dx = 0; dx < 4; ++dx)
          xin[dy][dx] = lds[(ic * 10 + row + dy) * 66 + w0 + dx];

      const float* wbase = Wt + ((size_t)oc0 * C_IN + (c0 + ic)) * 9;
#pragma unroll
      for (int oc = 0; oc < TB_OC; ++oc) {
        const float* w9 = wbase + (size_t)oc * (C_IN * 9);  // uniform -> s_load
#pragma unroll
        for (int dy = 0; dy < 3; ++dy) {
#pragma unroll
          for (int dx = 0; dx < 3; ++dx) {
            const float wv = w9[dy * 3 + dx];
            acc[oc][0] = fmaf(xin[dy][dx], wv, acc[oc][0]);
            acc[oc][1] = fmaf(xin[dy][dx + 1], wv, acc[oc][1]);
          }
        }
      }
    }
  }

  // ---- epilogue: bias (scaled by #children) + store ----
#pragma unroll
  for (int oc = 0; oc < TB_OC; ++oc) {
    const float b = bias[oc0 + oc] * bmult;
    float2 v = make_float2(acc[oc][0] + b, acc[oc][1] + b);
    const size_t off =
        ((size_t)(n * 128 + oc0 + oc) * 64 + (h0 + row)) * 64 + w0;
    *reinterpret_cast<float2*>(out + off) = v;
  }
}

extern "C" void kernel_launch(void* const* d_in, const int* in_sizes, int n_in,
                              void* d_out, int out_size, void* d_ws,
                              size_t ws_size, hipStream_t stream) {
  const float* x   = (const float*)d_in[0];
  const float* W0  = (const float*)d_in[1];
  const float* b0  = (const float*)d_in[2];
  const float* Wn  = (const float*)d_in[3];
  const float* bn  = (const float*)d_in[4];
  float* OUT = (float*)d_out;

  const size_t ACT = (size_t)8 * 128 * 64 * 64;  // 4,194,304 elems
  float* B0 = (float*)d_ws;
  float* B1 = B0 + ACT;

  const size_t WSZ = (size_t)128 * 128 * 9;

  dim3 grid(64 / TB_H, 128 / TB_OC, 8);
  dim3 block(256);

  // stage 0: stem, 64 -> 128 channels, into OUT (A0)
  conv3x3_sum_kernel<64><<<grid, block, 0, stream>>>(
      x, nullptr, W0, b0, 1.f, OUT);
  // node 1: children {0}          A1 = B0
  conv3x3_sum_kernel<128><<<grid, block, 0, stream>>>(
      OUT, nullptr, Wn + 0 * WSZ, bn + 0 * 128, 1.f, B0);
  // node 2: children {0,1}        A2 = B1
  conv3x3_sum_kernel<128><<<grid, block, 0, stream>>>(
      OUT, B0, Wn + 1 * WSZ, bn + 1 * 128, 2.f, B1);
  // node 3: children {1,2}        A3 = OUT (A0 dead)
  conv3x3_sum_kernel<128><<<grid, block, 0, stream>>>(
      B0, B1, Wn + 2 * WSZ, bn + 2 * 128, 2.f, OUT);
  // node 4: children {2,3}        A4 = B0 (A1 dead)
  conv3x3_sum_kernel<128><<<grid, block, 0, stream>>>(
      B1, OUT, Wn + 3 * WSZ, bn + 3 * 128, 2.f, B0);
  // node 5: children {3,4}        A5 = B1 (A2 dead)
  conv3x3_sum_kernel<128><<<grid, block, 0, stream>>>(
      OUT, B0, Wn + 4 * WSZ, bn + 4 * 128, 2.f, B1);
  // node 6: children {4,5}        A6 = OUT (A3 dead; reads B0,B1 only)
  conv3x3_sum_kernel<128><<<grid, block, 0, stream>>>(
      B0, B1, Wn + 5 * WSZ, bn + 5 * 128, 2.f, OUT);

  (void)in_sizes; (void)n_in; (void)out_size; (void)ws_size;
}

// Round 2
// 146.412 us; speedup vs baseline: 14.7731x; 14.7731x over previous
//
#include <hip/hip_runtime.h>

// GraphConvBlock via bf16 MFMA implicit GEMM.
// - Linearity: conv(a,W)+conv(b,W)+2b == conv(a+b,W)+2*bias (sum in f32 at staging).
// - Activations between stages: bf16, padded NHWC [n][66][66][C] with halo zeros
//   (no boundary branches) and ic-XOR swizzle baked into the GLOBAL layout so
//   LDS B-fragment ds_read_b128 are bank-conflict-free.
// - Weights prepacked once per launch: bf16 chunks [128 oc][32 ic] ic-contiguous.
// - MFMA: mfma_f32_16x16x32_bf16. Wave tile 64oc x 32pix (4Mx2N frags).

typedef __bf16 bf16x8 __attribute__((ext_vector_type(8)));
typedef float f32x4 __attribute__((ext_vector_type(4)));

union U4 { uint4 u; bf16x8 b; };

__device__ inline unsigned pk_bf16(float lo, float hi) {
  unsigned r;
  asm volatile("v_cvt_pk_bf16_f32 %0, %1, %2" : "=v"(r) : "v"(lo), "v"(hi));
  return r;
}

__device__ inline unsigned addpk(unsigned a, unsigned b) {
  float alo = __builtin_bit_cast(float, a << 16);
  float ahi = __builtin_bit_cast(float, a & 0xFFFF0000u);
  float blo = __builtin_bit_cast(float, b << 16);
  float bhi = __builtin_bit_cast(float, b & 0xFFFF0000u);
  return pk_bf16(alo + blo, ahi + bhi);
}

// ---------------- weight repack: fp32 OIHW -> bf16 chunks [128][16 words] ----
// chunk order: stem (CIN=64): 18 chunks; node s: 36 chunks at 18+(s-1)*36.
// within stage: k -> half h=k/18, c18=k%18, dydx=c18>>1, ics=c18&1.
#define WB_TOTAL_WORDS (234 * 2048)
__global__ void repack_w(const float* __restrict__ W0,
                         const float* __restrict__ Wn,
                         unsigned* __restrict__ Wb) {
  unsigned gid = blockIdx.x * 256 + threadIdx.x;
  if (gid >= WB_TOTAL_WORDS) return;
  int chunk = gid >> 11, w = gid & 2047;
  int oc = w >> 4, icl = w & 15;
  const float* src;
  int CIN, k;
  if (chunk < 18) { src = W0; CIN = 64; k = chunk; }
  else {
    int s = (chunk - 18) / 36;
    src = Wn + (size_t)s * 128 * 128 * 9;
    CIN = 128;
    k = (chunk - 18) % 36;
  }
  int h = k / 18, c18 = k % 18;
  int d = c18 >> 1, dy = d / 3, dx = d % 3;
  int ic = h * 64 + (c18 & 1) * 32 + icl * 2;
  float lo = src[(((size_t)oc * CIN + ic) * 3 + dy) * 3 + dx];
  float hi = src[(((size_t)oc * CIN + ic + 1) * 3 + dy) * 3 + dx];
  Wb[gid] = pk_bf16(lo, hi);
}

// ---------------- transform x: fp32 NCHW -> bf16 padded swizzled NHWC(64ch) --
__global__ void transform_x(const float* __restrict__ x, unsigned* __restrict__ T) {
  __shared__ float xl[64][65];
  int n = blockIdx.y, h = blockIdx.x, tid = threadIdx.x;
#pragma unroll
  for (int k = 0; k < 16; ++k) {
    int idx = tid + k * 256;
    int ic = idx >> 6, w = idx & 63;
    xl[w][ic] = x[(((size_t)n * 64 + ic) * 64 + h) * 64 + w];
  }
  __syncthreads();
#pragma unroll
  for (int k = 0; k < 8; ++k) {
    int idx = tid + k * 256;
    int w = idx >> 5, icp = idx & 31;
    unsigned v = pk_bf16(xl[w][icp * 2], xl[w][icp * 2 + 1]);
    int wp = w + 1;
    int pos = icp ^ ((wp & 7) << 2);
    T[(((size_t)n * 66 + (h + 1)) * 66 + wp) * 32 + pos] = v;
  }
}

// ---------------- main conv stage -------------------------------------------
// block: 256 thr (4 waves), output 128oc x 64pix (one (n,h0) row).
// wave (wm,wn): oc0=wm*64, pix0=wn*32; acc 4Mx2N frags of 16x16.
template <int CIN, bool DUAL, bool OUTF32>
__global__ __launch_bounds__(256, 3) void conv_stage(
    const unsigned* __restrict__ in0, const unsigned* __restrict__ in1,
    const unsigned* __restrict__ wb, const float* __restrict__ bias,
    float bmult, void* __restrict__ outp) {
  constexpr int WPP = CIN / 2;      // u32 words per pixel in input buffer
  constexpr int HALVES = CIN / 64;
  __shared__ unsigned Alds[3 * 66 * 32];   // acts: 3 rows x 66 cols x 64ch
  __shared__ unsigned Wlds[2][128 * 20];   // weights dbuf, +4 word pad

  const int tid = threadIdx.x;
  const int lane = tid & 63;
  const int wav = tid >> 6;
  const int wm = wav >> 1, wn = wav & 1;
  const int bid = blockIdx.x;
  const int n = bid & 7;            // XCD-chunked: same n -> same XCD (L2 locality)
  const int h0 = bid >> 3;
  const int l15 = lane & 15, q = lane >> 4;

  f32x4 acc[4][2];
#pragma unroll
  for (int m = 0; m < 4; ++m)
#pragma unroll
    for (int p = 0; p < 2; ++p) acc[m][p] = (f32x4)0.f;

  // weight chunk prefetch registers (8KB/chunk, 32B/thread)
  uint4 wr0, wr1;
  {
    const uint4* s = (const uint4*)(wb + (size_t)tid * 8);
    wr0 = s[0]; wr1 = s[1];
  }

  for (int half = 0; half < HALVES; ++half) {
    __syncthreads();  // Alds readers of previous half done
    // ---- stage acts: 3 rows x 66 cols x 32 words (verbatim swizzled copy) ----
    for (int i = tid; i < 1584; i += 256) {
      int r = i / 528, rem = i % 528;
      int wp = rem >> 3, q4 = rem & 7;
      size_t goff = (((size_t)n * 66 + (h0 + r)) * 66 + wp) * WPP + half * 32 + q4 * 4;
      uint4 v = *(const uint4*)(in0 + goff);
      if (DUAL) {
        uint4 v1 = *(const uint4*)(in1 + goff);
        v.x = addpk(v.x, v1.x); v.y = addpk(v.y, v1.y);
        v.z = addpk(v.z, v1.z); v.w = addpk(v.w, v1.w);
      }
      *(uint4*)&Alds[(r * 66 + wp) * 32 + q4 * 4] = v;
    }
    // ---- 18 weight-chunk phases per half: dbuf, one barrier per phase ----
    for (int c = 0; c < 18; ++c) {
      int buf = c & 1;
      {  // commit prefetched chunk to LDS (padded rows of 20 words)
        int oc = tid >> 1, icl = (tid & 1) * 8;
        unsigned* dst = &Wlds[buf][oc * 20 + icl];
        *(uint4*)dst = wr0;
        *(uint4*)(dst + 4) = wr1;
      }
      int nk = half * 18 + c + 1;
      if (nk < HALVES * 18) {
        const uint4* s = (const uint4*)(wb + (size_t)nk * 2048 + (size_t)tid * 8);
        wr0 = s[0]; wr1 = s[1];
      }
      __syncthreads();

      const int d = c >> 1, ics = c & 1;
      const int dy = d / 3, dx = d % 3;

      bf16x8 a[4];
#pragma unroll
      for (int m = 0; m < 4; ++m) {
        U4 u;
        u.u = *(const uint4*)&Wlds[buf][(wm * 64 + m * 16 + l15) * 20 + q * 4];
        a[m] = u.b;
      }
      bf16x8 b[2];
#pragma unroll
      for (int p = 0; p < 2; ++p) {
        int col = wn * 32 + p * 16 + l15 + dx;
        int pos = (ics * 16 + q * 4) ^ ((col & 7) << 2);
        U4 u;
        u.u = *(const uint4*)&Alds[(dy * 66 + col) * 32 + pos];
        b[p] = u.b;
      }
#pragma unroll
      for (int m = 0; m < 4; ++m)
#pragma unroll
        for (int p = 0; p < 2; ++p)
          acc[m][p] = __builtin_amdgcn_mfma_f32_16x16x32_bf16(a[m], b[p], acc[m][p], 0, 0, 0);
    }
  }

  // ---- epilogue ----
  if (OUTF32) {
    float* out = (float*)outp;
#pragma unroll
    for (int m = 0; m < 4; ++m) {
      int oc0 = wm * 64 + m * 16 + q * 4;
      float4 bb = *(const float4*)&bias[oc0];
#pragma unroll
      for (int p = 0; p < 2; ++p) {
        int w = wn * 32 + p * 16 + l15;
#pragma unroll
        for (int j = 0; j < 4; ++j) {
          out[(((size_t)n * 128 + oc0 + j) * 64 + h0) * 64 + w] =
              acc[m][p][j] + ((float*)&bb)[j] * bmult;
        }
      }
    }
  } else {
    unsigned* out = (unsigned*)outp;
#pragma unroll
    for (int m = 0; m < 4; ++m) {
      int oc0 = wm * 64 + m * 16 + q * 4;
      float4 bb = *(const float4*)&bias[oc0];
#pragma unroll
      for (int p = 0; p < 2; ++p) {
        int w = wn * 32 + p * 16 + l15;
        int wp = w + 1;
        unsigned lo = pk_bf16(acc[m][p][0] + bb.x * bmult, acc[m][p][1] + bb.y * bmult);
        unsigned hi = pk_bf16(acc[m][p][2] + bb.z * bmult, acc[m][p][3] + bb.w * bmult);
        int icp0 = oc0 >> 1;
        int pos = icp0 ^ ((wp & 7) << 2);
        size_t base = (((size_t)n * 66 + (h0 + 1)) * 66 + wp) * 64;
        *(uint2*)&out[base + pos] = make_uint2(lo, hi);
      }
    }
  }
}

// ---------------- launch ------------------------------------------------------
extern "C" void kernel_launch(void* const* d_in, const int* in_sizes, int n_in,
                              void* d_out, int out_size, void* d_ws,
                              size_t ws_size, hipStream_t stream) {
  const float* x = (const float*)d_in[0];
  const float* W0 = (const float*)d_in[1];
  const float* b0 = (const float*)d_in[2];
  const float* Wn = (const float*)d_in[3];
  const float* bn = (const float*)d_in[4];

  const size_t ACTW = (size_t)8 * 66 * 66 * 64;   // u32 words per 128-ch act buffer
  const size_t TW = (size_t)8 * 66 * 66 * 32;     // u32 words for 64-ch stem input
  unsigned* B0 = (unsigned*)d_ws;
  unsigned* B1 = B0 + ACTW;
  unsigned* B2 = B1 + ACTW;
  unsigned* T = B2 + ACTW;
  unsigned* Wb = T + TW;

  // zero act buffers + T (halos must be zero; interiors fully rewritten)
  hipMemsetAsync(d_ws, 0, (3 * ACTW + TW) * sizeof(unsigned), stream);

  repack_w<<<(WB_TOTAL_WORDS + 255) / 256, 256, 0, stream>>>(W0, Wn, Wb);
  transform_x<<<dim3(64, 8), 256, 0, stream>>>(x, T);

  dim3 grid(512), blk(256);
  const size_t NW = 36 * 2048;  // words per node-stage weight block
  // stem: T -> B0
  conv_stage<64, false, false><<<grid, blk, 0, stream>>>(T, T, Wb, b0, 1.f, B0);
  // node1 {0}: B0 -> B1
  conv_stage<128, false, false><<<grid, blk, 0, stream>>>(B0, B0, Wb + 18 * 2048, bn + 0, 1.f, B1);
  // node2 {0,1}: B0+B1 -> B2
  conv_stage<128, true, false><<<grid, blk, 0, stream>>>(B0, B1, Wb + 18 * 2048 + 1 * NW, bn + 128, 2.f, B2);
  // node3 {1,2}: B1+B2 -> B0
  conv_stage<128, true, false><<<grid, blk, 0, stream>>>(B1, B2, Wb + 18 * 2048 + 2 * NW, bn + 256, 2.f, B0);
  // node4 {2,3}: B2+B0 -> B1
  conv_stage<128, true, false><<<grid, blk, 0, stream>>>(B2, B0, Wb + 18 * 2048 + 3 * NW, bn + 384, 2.f, B1);
  // node5 {3,4}: B0+B1 -> B2
  conv_stage<128, true, false><<<grid, blk, 0, stream>>>(B0, B1, Wb + 18 * 2048 + 4 * NW, bn + 512, 2.f, B2);
  // node6 {4,5}: B1+B2 -> d_out (fp32 NCHW)
  conv_stage<128, true, true><<<grid, blk, 0, stream>>>(B1, B2, Wb + 18 * 2048 + 5 * NW, bn + 640, 2.f, d_out);

  (void)in_sizes; (void)n_in; (void)out_size; (void)ws_size;
}